// Round 12
// baseline (276.390 us; speedup 1.0000x reference)
//
#include <hip/hip_runtime.h>
#include <hip/hip_bf16.h>
#include <cstdint>
#include <cstddef>

#define N_NODES 10000
#define M_PAD   10240   // 80 panels of 128; 80 % 8 == 0 -> panel%8 = XCD under round-robin
#define HEADS   4

typedef __bf16 bfrag8 __attribute__((ext_vector_type(8)));
typedef __bf16 bfrag2 __attribute__((ext_vector_type(2)));
typedef float  floatx4 __attribute__((ext_vector_type(4)));
typedef float  floatx2 __attribute__((ext_vector_type(2)));

// ---------------- fused prep: x->bf16 pad, 5 weight transposes (8k per thread,
// 16B stores), edge degree count. deg[] zeroed by hipMemsetAsync beforehand. ----
#define S0V (M_PAD * 512 / 8)   // xb, 8 elements per thread
#define S1E (512 * 512 / 8)     // W1T
#define S2E (512 * 512 / 8)     // W2T
#define S3E (512 * 128 / 8)     // W3T
#define S4E (128 * 256 / 8)     // WlT
#define S5E (512 * 256 / 8)     // WrT

__global__ __launch_bounds__(256) void prep(const float* __restrict__ x,
                                            const float* __restrict__ W1,
                                            const float* __restrict__ W2,
                                            const float* __restrict__ W3,
                                            const float* __restrict__ Wl,
                                            const float* __restrict__ Wr,
                                            const int* __restrict__ edst, int E,
                                            __bf16* __restrict__ xb,
                                            __bf16* __restrict__ W1T,
                                            __bf16* __restrict__ W2T,
                                            __bf16* __restrict__ W3T,
                                            __bf16* __restrict__ WlT,
                                            __bf16* __restrict__ WrT,
                                            int* __restrict__ deg) {
    int i = blockIdx.x * 256 + threadIdx.x;
    if (i < S0V) {
        int base = i * 8;
        int row = base >> 9;
        bfrag8 r = {};
        if (row < N_NODES) {
            float4 f0 = ((const float4*)x)[i * 2];
            float4 f1 = ((const float4*)x)[i * 2 + 1];
            r[0] = (__bf16)f0.x; r[1] = (__bf16)f0.y; r[2] = (__bf16)f0.z; r[3] = (__bf16)f0.w;
            r[4] = (__bf16)f1.x; r[5] = (__bf16)f1.y; r[6] = (__bf16)f1.z; r[7] = (__bf16)f1.w;
        }
        *(bfrag8*)(xb + base) = r;
    } else if ((i -= S0V) < S1E) {          // W1: K=512, N=512
        int n = i & 511, kb = (i >> 9) * 8;
        bfrag8 r;
#pragma unroll
        for (int t = 0; t < 8; ++t) r[t] = (__bf16)W1[(kb + t) * 512 + n];
        *(bfrag8*)(W1T + n * 512 + kb) = r;
    } else if ((i -= S1E) < S2E) {          // W2: K=512, N=512
        int n = i & 511, kb = (i >> 9) * 8;
        bfrag8 r;
#pragma unroll
        for (int t = 0; t < 8; ++t) r[t] = (__bf16)W2[(kb + t) * 512 + n];
        *(bfrag8*)(W2T + n * 512 + kb) = r;
    } else if ((i -= S2E) < S3E) {          // W3: K=512, N=128
        int n = i & 127, kb = (i >> 7) * 8;
        bfrag8 r;
#pragma unroll
        for (int t = 0; t < 8; ++t) r[t] = (__bf16)W3[(kb + t) * 128 + n];
        *(bfrag8*)(W3T + n * 512 + kb) = r;
    } else if ((i -= S3E) < S4E) {          // Wl: K=128, N=256
        int n = i & 255, kb = (i >> 8) * 8;
        bfrag8 r;
#pragma unroll
        for (int t = 0; t < 8; ++t) r[t] = (__bf16)Wl[(kb + t) * 256 + n];
        *(bfrag8*)(WlT + n * 128 + kb) = r;
    } else if ((i -= S4E) < S5E) {          // Wr: K=512, N=256
        int n = i & 255, kb = (i >> 8) * 8;
        bfrag8 r;
#pragma unroll
        for (int t = 0; t < 8; ++t) r[t] = (__bf16)Wr[(kb + t) * 256 + n];
        *(bfrag8*)(WrT + n * 512 + kb) = r;
    } else if ((i -= S5E) < E) {
        atomicAdd(&deg[edst[i]], 1);
    }
}

// ---------------- CSR build ----------------

__global__ __launch_bounds__(256) void scan_kernel(const int* __restrict__ deg,
                                                   int* __restrict__ rowptr,
                                                   int* __restrict__ cursor, int n) {
    __shared__ int wtot[4], woff[4];
    int t = threadIdx.x, lane = t & 63, wv = t >> 6;
    int chunk = (n + 255) / 256;
    int beg = t * chunk, end = beg + chunk; if (end > n) end = n; if (beg > n) beg = n;
    int s = 0;
    for (int i = beg; i < end; ++i) s += deg[i] + 1;   // +1 self-loop
    int v = s;
#pragma unroll
    for (int off = 1; off < 64; off <<= 1) {
        int o = __shfl_up(v, off);
        if (lane >= off) v += o;
    }
    if (lane == 63) wtot[wv] = v;
    __syncthreads();
    if (t == 0) {
        int r = 0;
#pragma unroll
        for (int i = 0; i < 4; ++i) { woff[i] = r; r += wtot[i]; }
        rowptr[n] = r;
    }
    __syncthreads();
    int off = woff[wv] + v - s;     // exclusive prefix
    for (int i = beg; i < end; ++i) {
        rowptr[i] = off; cursor[i] = off;
        off += deg[i] + 1;
    }
}

__global__ __launch_bounds__(256) void scatter_kernel(const int* __restrict__ src,
                                                      const int* __restrict__ dst, int E, int n,
                                                      int* __restrict__ cursor,
                                                      int* __restrict__ csr) {
    int i = blockIdx.x * 256 + threadIdx.x;
    if (i < E) {
        int pos = atomicAdd(&cursor[dst[i]], 1);
        csr[pos] = src[i];
    } else if (i < E + n) {
        int v = i - E;
        int pos = atomicAdd(&cursor[v], 1);
        csr[pos] = v;                              // self-loop
    }
}

// ---------------- MFMA GEMM K-loop, BK=64, tile 128(M) x 16*NT(N) ----------------

template <int NT>
__device__ __forceinline__ void gemm_loop(const __bf16* __restrict__ A,
                                          const __bf16* __restrict__ BT, int K,
                                          int m0, int n0, int wave, int lane,
                                          __bf16* As, __bf16* Bs,
                                          floatx4 (&acc)[2][NT]) {
    int r = wave * 8 + (lane >> 3);          // 0..31 staging row
    int kof = (lane & 7) * 8;
    const __bf16* gA = A + (size_t)(m0 + r) * K + kof;
    const __bf16* gB = BT + (size_t)(n0 + r) * K + kof;
    __bf16* lA = As + r * 64 + kof;
    __bf16* lB = Bs + r * 64 + kof;
    const __bf16* fA = As + (wave * 32 + (lane & 15)) * 64 + (lane >> 4) * 8;
    const __bf16* fB = Bs + (lane & 15) * 64 + (lane >> 4) * 8;

    for (int k0 = 0; k0 < K; k0 += 64) {
#pragma unroll
        for (int u = 0; u < 4; ++u)
            __builtin_amdgcn_global_load_lds(
                (const __attribute__((address_space(1))) void*)(gA + (size_t)u * 32 * K),
                (__attribute__((address_space(3))) void*)(lA + u * 32 * 64), 16, 0, 0);
#pragma unroll
        for (int u = 0; u < NT / 2; ++u)
            __builtin_amdgcn_global_load_lds(
                (const __attribute__((address_space(1))) void*)(gB + (size_t)u * 32 * K),
                (__attribute__((address_space(3))) void*)(lB + u * 32 * 64), 16, 0, 0);
        gA += 64; gB += 64;
        __syncthreads();

#pragma unroll
        for (int ks = 0; ks < 2; ++ks) {
            bfrag8 a0 = *(const bfrag8*)(fA + ks * 32);
            bfrag8 a1 = *(const bfrag8*)(fA + 16 * 64 + ks * 32);
#pragma unroll
            for (int nt = 0; nt < NT; ++nt) {
                bfrag8 b = *(const bfrag8*)(fB + nt * 16 * 64 + ks * 32);
                acc[0][nt] = __builtin_amdgcn_mfma_f32_16x16x32_bf16(a0, b, acc[0][nt], 0, 0, 0);
                acc[1][nt] = __builtin_amdgcn_mfma_f32_16x16x32_bf16(a1, b, acc[1][nt], 0, 0, 0);
            }
        }
        __syncthreads();
    }
}

// GEMM: fp8 e4m3 out (for gather) + fused attn-logit PARTIALS (fp32-exact).
// 128x64 tile; grid (M_PAD/128, N/64) -- panel fast dim -> xcd = panel % 8 (L2 affinity).
// Partials interleaved: esp[(row*H+head)*2 + half], summed as float2 in gather_agg.
__global__ __launch_bounds__(256) void gemm_h(const __bf16* __restrict__ A,
                                              const __bf16* __restrict__ BT,
                                              unsigned char* __restrict__ C8,
                                              int N, int K, int H,
                                              const float* __restrict__ as_,
                                              const float* __restrict__ ad_,
                                              float* __restrict__ esp,
                                              float* __restrict__ edp) {
    __shared__ __align__(16) __bf16 As[128 * 64];
    __shared__ __align__(16) __bf16 Bs[64 * 64];
    int tid = threadIdx.x, wave = tid >> 6, lane = tid & 63;
    int m0 = blockIdx.x * 128, n0 = blockIdx.y * 64;
    floatx4 acc[2][4] = {};
    gemm_loop<4>(A, BT, K, m0, n0, wave, lane, As, Bs, acc);

    int crow = m0 + wave * 32 + (lane >> 4) * 4;
    int ccol = n0 + (lane & 15);
#pragma unroll
    for (int mt = 0; mt < 2; ++mt)
#pragma unroll
        for (int nt = 0; nt < 4; ++nt)
#pragma unroll
            for (int r = 0; r < 4; ++r) {
                float v = acc[mt][nt][r];
                size_t o = (size_t)(crow + mt * 16 + r) * N + ccol + nt * 16;
                int p = __builtin_amdgcn_cvt_pk_fp8_f32(v, v, 0, false);
                C8[o] = (unsigned char)(p & 0xff);
            }

    // fused logit partials: this block covers channels [(n0&64), (n0&64)+64) of head n0>>7
    int head = n0 >> 7;
    int half = (n0 >> 6) & 1;
    float a_sv[4], a_dv[4];
#pragma unroll
    for (int nt = 0; nt < 4; ++nt) {
        int cin = (n0 & 64) + nt * 16 + (lane & 15);
        a_sv[nt] = as_[head * 128 + cin];
        a_dv[nt] = ad_[head * 128 + cin];
    }
#pragma unroll
    for (int mt = 0; mt < 2; ++mt)
#pragma unroll
        for (int r = 0; r < 4; ++r) {
            float ps = 0.f, pd = 0.f;
#pragma unroll
            for (int nt = 0; nt < 4; ++nt) {
                float v = acc[mt][nt][r];
                ps += v * a_sv[nt];
                pd += v * a_dv[nt];
            }
#pragma unroll
            for (int off = 8; off; off >>= 1) {
                ps += __shfl_xor(ps, off);
                pd += __shfl_xor(pd, off);
            }
            if ((lane & 15) == 0) {
                int row = crow + mt * 16 + r;
                esp[(size_t)(row * H + head) * 2 + half] = ps;
                edp[(size_t)(row * H + head) * 2 + half] = pd;
            }
        }
}

// fused final: C = A1@B1T^T + A2@B2T^T + bias1 + bias2, fp32 out, rows < M
// grid (M_PAD/128, N/64), panel-fast for XCD affinity.
__global__ __launch_bounds__(256) void gemm_final(const __bf16* __restrict__ A1,
                                                  const __bf16* __restrict__ B1T, int K1,
                                                  const __bf16* __restrict__ A2,
                                                  const __bf16* __restrict__ B2T, int K2,
                                                  float* __restrict__ C,
                                                  const float* __restrict__ bias1,
                                                  const float* __restrict__ bias2,
                                                  int M, int N) {
    __shared__ __align__(16) __bf16 As[128 * 64];
    __shared__ __align__(16) __bf16 Bs[64 * 64];
    int tid = threadIdx.x, wave = tid >> 6, lane = tid & 63;
    int m0 = blockIdx.x * 128, n0 = blockIdx.y * 64;
    floatx4 acc[2][4] = {};
    gemm_loop<4>(A1, B1T, K1, m0, n0, wave, lane, As, Bs, acc);
    gemm_loop<4>(A2, B2T, K2, m0, n0, wave, lane, As, Bs, acc);

    int crow = m0 + wave * 32 + (lane >> 4) * 4;
    int ccol = n0 + (lane & 15);
#pragma unroll
    for (int mt = 0; mt < 2; ++mt)
#pragma unroll
        for (int nt = 0; nt < 4; ++nt)
#pragma unroll
            for (int r = 0; r < 4; ++r) {
                int row = crow + mt * 16 + r;
                int col = ccol + nt * 16;
                if (row < M)
                    C[(size_t)row * N + col] = acc[mt][nt][r] + bias1[col] + bias2[col];
            }
}

// ---------------- fused softmax + weighted gather, fp8 H ----------------
// One wave per node, all heads. All edges processed in masked 8-chunks (clamped index,
// zero weight for pad slots) with a depth-2 software pipeline: chunk c+1's csr/esp/row
// loads are issued before chunk c's compute, hiding the dependent-load latency chain.

template <int H>
__global__ __launch_bounds__(256) void gather_agg(const unsigned char* __restrict__ H8,
                                                  const float* __restrict__ esp,
                                                  const float* __restrict__ edp,
                                                  const int* __restrict__ rowptr,
                                                  const int* __restrict__ csr,
                                                  const float* __restrict__ bias,
                                                  __bf16* __restrict__ outb) {
    constexpr int F = H * 128;
    constexpr int CH = F / 64;          // 8 or 2
    int wave = threadIdx.x >> 6, lane = threadIdx.x & 63;
    int node = blockIdx.x * 4 + wave;
    if (node >= M_PAD) return;
    int hsel = (H == 4) ? (lane >> 4) : 0;
    __bf16* op = outb + (size_t)node * F + lane * CH;
    if (node >= N_NODES) {
        if (H == 4) { bfrag8 z = {}; *(bfrag8*)op = z; }
        else        { bfrag2 z = {}; *(bfrag2*)op = z; }
        return;
    }
    const unsigned char* hp = H8 + lane * CH;
    const float2* es2 = (const float2*)esp;
    float2 dv = ((const float2*)edp)[node * H + hsel];
    float edv = dv.x + dv.y;
    int beg = rowptr[node], end = rowptr[node + 1];
    int nch = (end - beg + 7) >> 3;     // >= 1 (self-loop guarantees degree >= 1)
    float acc[CH] = {};
    float wsum = 0.f;
    int j = beg;

    if constexpr (H == 4) {
        int s0[8]; float2 e0[8]; uint2 p0[8];
#pragma unroll
        for (int u = 0; u < 8; ++u) s0[u] = csr[(j + u < end) ? j + u : end - 1];
#pragma unroll
        for (int u = 0; u < 8; ++u) e0[u] = es2[s0[u] * H + hsel];
#pragma unroll
        for (int u = 0; u < 8; ++u) p0[u] = *(const uint2*)(hp + (size_t)s0[u] * F);
        for (int c = 0; c < nch; ++c) {
            int s1[8]; float2 e1[8]; uint2 p1[8];
            int jn = j + 8;
            bool more = (c + 1 < nch);
            if (more) {
#pragma unroll
                for (int u = 0; u < 8; ++u) s1[u] = csr[(jn + u < end) ? jn + u : end - 1];
#pragma unroll
                for (int u = 0; u < 8; ++u) e1[u] = es2[s1[u] * H + hsel];
#pragma unroll
                for (int u = 0; u < 8; ++u) p1[u] = *(const uint2*)(hp + (size_t)s1[u] * F);
            }
#pragma unroll
            for (int u = 0; u < 8; ++u) {
                float t = e0[u].x + e0[u].y + edv;
                t = t > 0.f ? t : 0.2f * t;            // leaky_relu(0.2)
                float wgt = (j + u < end) ? __expf(t) : 0.f;
                wsum += wgt;
                floatx2 f0 = __builtin_amdgcn_cvt_pk_f32_fp8(p0[u].x, false);
                floatx2 f1 = __builtin_amdgcn_cvt_pk_f32_fp8(p0[u].x, true);
                floatx2 f2 = __builtin_amdgcn_cvt_pk_f32_fp8(p0[u].y, false);
                floatx2 f3 = __builtin_amdgcn_cvt_pk_f32_fp8(p0[u].y, true);
                acc[0] += wgt * f0[0]; acc[1] += wgt * f0[1];
                acc[2] += wgt * f1[0]; acc[3] += wgt * f1[1];
                acc[4] += wgt * f2[0]; acc[5] += wgt * f2[1];
                acc[6] += wgt * f3[0]; acc[7] += wgt * f3[1];
            }
            if (more) {
#pragma unroll
                for (int u = 0; u < 8; ++u) { s0[u] = s1[u]; e0[u] = e1[u]; p0[u] = p1[u]; }
            }
            j = jn;
        }
    } else {
        int s0[8]; float2 e0[8]; unsigned short p0[8];
#pragma unroll
        for (int u = 0; u < 8; ++u) s0[u] = csr[(j + u < end) ? j + u : end - 1];
#pragma unroll
        for (int u = 0; u < 8; ++u) e0[u] = es2[s0[u] * H + hsel];
#pragma unroll
        for (int u = 0; u < 8; ++u) p0[u] = *(const unsigned short*)(hp + (size_t)s0[u] * F);
        for (int c = 0; c < nch; ++c) {
            int s1[8]; float2 e1[8]; unsigned short p1[8];
            int jn = j + 8;
            bool more = (c + 1 < nch);
            if (more) {
#pragma unroll
                for (int u = 0; u < 8; ++u) s1[u] = csr[(jn + u < end) ? jn + u : end - 1];
#pragma unroll
                for (int u = 0; u < 8; ++u) e1[u] = es2[s1[u] * H + hsel];
#pragma unroll
                for (int u = 0; u < 8; ++u) p1[u] = *(const unsigned short*)(hp + (size_t)s1[u] * F);
            }
#pragma unroll
            for (int u = 0; u < 8; ++u) {
                float t = e0[u].x + e0[u].y + edv;
                t = t > 0.f ? t : 0.2f * t;
                float wgt = (j + u < end) ? __expf(t) : 0.f;
                wsum += wgt;
                floatx2 f0 = __builtin_amdgcn_cvt_pk_f32_fp8((int)p0[u], false);
                acc[0] += wgt * f0[0]; acc[1] += wgt * f0[1];
            }
            if (more) {
#pragma unroll
                for (int u = 0; u < 8; ++u) { s0[u] = s1[u]; e0[u] = e1[u]; p0[u] = p1[u]; }
            }
            j = jn;
        }
    }

    float inv = 1.f / (wsum + 1e-16f);
    if (H == 4) {
        bfrag8 r;
#pragma unroll
        for (int k = 0; k < 8; ++k) {
            float o = acc[k] * inv + bias[lane * 8 + k];
            o = o > 0.f ? o : __expf(o) - 1.f;     // ELU
            r[k] = (__bf16)o;
        }
        *(bfrag8*)op = r;
    } else {
        bfrag2 r;
#pragma unroll
        for (int k = 0; k < 2; ++k) {
            float o = acc[k] * inv + bias[lane * 2 + k];
            o = o > 0.f ? o : __expf(o) - 1.f;
            r[k] = (__bf16)o;
        }
        *(bfrag2*)op = r;
    }
}

// ---------------- launch ----------------

extern "C" void kernel_launch(void* const* d_in, const int* in_sizes, int n_in,
                              void* d_out, int out_size, void* d_ws, size_t ws_size,
                              hipStream_t stream) {
    const float* x   = (const float*)d_in[0];
    const float* W1  = (const float*)d_in[1];
    const float* a1s = (const float*)d_in[2];
    const float* a1d = (const float*)d_in[3];
    const float* b1  = (const float*)d_in[4];
    const float* W2  = (const float*)d_in[5];
    const float* a2s = (const float*)d_in[6];
    const float* a2d = (const float*)d_in[7];
    const float* b2  = (const float*)d_in[8];
    const float* W3  = (const float*)d_in[9];
    const float* a3s = (const float*)d_in[10];
    const float* a3d = (const float*)d_in[11];
    const float* b3  = (const float*)d_in[12];
    const float* Wl  = (const float*)d_in[13];
    const float* bl  = (const float*)d_in[14];
    const float* Wr  = (const float*)d_in[15];
    const float* br  = (const float*)d_in[16];
    const int*   ei  = (const int*)d_in[17];
    const int E = in_sizes[17] / 2;
    const int* esrc = ei;
    const int* edst = ei + E;
    const int slots = E + N_NODES;
    float* out = (float*)d_out;

    char* w = (char*)d_ws;
    auto alloc = [&](size_t b) { char* p = w; w += (b + 255) & ~(size_t)255; return p; };
    __bf16* xb  = (__bf16*)alloc((size_t)M_PAD * 512 * 2);
    __bf16* hb  = (__bf16*)alloc((size_t)M_PAD * 512 * 2);
    __bf16* hb3 = (__bf16*)alloc((size_t)M_PAD * 128 * 2);
    unsigned char* Hi8 = (unsigned char*)alloc((size_t)M_PAD * 512);
    __bf16* W1T = (__bf16*)alloc(512 * 512 * 2);
    __bf16* W2T = (__bf16*)alloc(512 * 512 * 2);
    __bf16* W3T = (__bf16*)alloc(128 * 512 * 2);
    __bf16* WlT = (__bf16*)alloc(256 * 128 * 2);
    __bf16* WrT = (__bf16*)alloc(256 * 512 * 2);
    float* esp    = (float*)alloc((size_t)2 * M_PAD * HEADS * 4);
    float* edp    = (float*)alloc((size_t)2 * M_PAD * HEADS * 4);
    int*   deg    = (int*)alloc(N_NODES * 4);
    int*   rowptr = (int*)alloc((N_NODES + 1) * 4);
    int*   cursor = (int*)alloc(N_NODES * 4);
    int*   csr    = (int*)alloc((size_t)slots * 4);

    (void)hipMemsetAsync(deg, 0, N_NODES * sizeof(int), stream);

    const int sp_total = S0V + S1E + S2E + S3E + S4E + S5E + E;
    prep<<<(sp_total + 255) / 256, 256, 0, stream>>>(x, W1, W2, W3, Wl, Wr, edst, E,
                                                     xb, W1T, W2T, W3T, WlT, WrT, deg);
    scan_kernel<<<1, 256, 0, stream>>>(deg, rowptr, cursor, N_NODES);
    scatter_kernel<<<(E + N_NODES + 255) / 256, 256, 0, stream>>>(esrc, edst, E, N_NODES,
                                                                  cursor, csr);

    // layer 1
    gemm_h<<<dim3(M_PAD / 128, 8), 256, 0, stream>>>(xb, W1T, Hi8, 512, 512, 4,
                                                     a1s, a1d, esp, edp);
    gather_agg<4><<<M_PAD / 4, 256, 0, stream>>>(Hi8, esp, edp, rowptr, csr, b1, hb);
    // layer 2
    gemm_h<<<dim3(M_PAD / 128, 8), 256, 0, stream>>>(hb, W2T, Hi8, 512, 512, 4,
                                                     a2s, a2d, esp, edp);
    gather_agg<4><<<M_PAD / 4, 256, 0, stream>>>(Hi8, esp, edp, rowptr, csr, b2, hb);
    // layer 3 (H=1)
    gemm_h<<<dim3(M_PAD / 128, 2), 256, 0, stream>>>(hb, W3T, Hi8, 128, 512, 1,
                                                     a3s, a3d, esp, edp);
    gather_agg<1><<<M_PAD / 4, 256, 0, stream>>>(Hi8, esp, edp, rowptr, csr, b3, hb3);
    // fused residual + final linear
    gemm_final<<<dim3(M_PAD / 128, 4), 256, 0, stream>>>(xb, WrT, 512, hb3, WlT, 128,
                                                         out, br, bl, N_NODES, 256);
}

// Round 13
// 267.007 us; speedup vs baseline: 1.0351x; 1.0351x over previous
//
#include <hip/hip_runtime.h>
#include <hip/hip_bf16.h>
#include <cstdint>
#include <cstddef>

#define N_NODES 10000
#define M_PAD   10240   // 80 panels of 128; 80 % 8 == 0 -> panel%8 = XCD under round-robin
#define HEADS   4

typedef __bf16 bfrag8 __attribute__((ext_vector_type(8)));
typedef __bf16 bfrag2 __attribute__((ext_vector_type(2)));
typedef float  floatx4 __attribute__((ext_vector_type(4)));
typedef float  floatx2 __attribute__((ext_vector_type(2)));

// ---------------- fused prep: x->bf16 pad, 5 weight transposes (8k per thread,
// 16B stores), edge degree count. deg[] zeroed by hipMemsetAsync beforehand. ----
#define S0V (M_PAD * 512 / 8)   // xb, 8 elements per thread
#define S1E (512 * 512 / 8)     // W1T
#define S2E (512 * 512 / 8)     // W2T
#define S3E (512 * 128 / 8)     // W3T
#define S4E (128 * 256 / 8)     // WlT
#define S5E (512 * 256 / 8)     // WrT

__global__ __launch_bounds__(256) void prep(const float* __restrict__ x,
                                            const float* __restrict__ W1,
                                            const float* __restrict__ W2,
                                            const float* __restrict__ W3,
                                            const float* __restrict__ Wl,
                                            const float* __restrict__ Wr,
                                            const int* __restrict__ edst, int E,
                                            __bf16* __restrict__ xb,
                                            __bf16* __restrict__ W1T,
                                            __bf16* __restrict__ W2T,
                                            __bf16* __restrict__ W3T,
                                            __bf16* __restrict__ WlT,
                                            __bf16* __restrict__ WrT,
                                            int* __restrict__ deg) {
    int i = blockIdx.x * 256 + threadIdx.x;
    if (i < S0V) {
        int base = i * 8;
        int row = base >> 9;
        bfrag8 r = {};
        if (row < N_NODES) {
            float4 f0 = ((const float4*)x)[i * 2];
            float4 f1 = ((const float4*)x)[i * 2 + 1];
            r[0] = (__bf16)f0.x; r[1] = (__bf16)f0.y; r[2] = (__bf16)f0.z; r[3] = (__bf16)f0.w;
            r[4] = (__bf16)f1.x; r[5] = (__bf16)f1.y; r[6] = (__bf16)f1.z; r[7] = (__bf16)f1.w;
        }
        *(bfrag8*)(xb + base) = r;
    } else if ((i -= S0V) < S1E) {          // W1: K=512, N=512
        int n = i & 511, kb = (i >> 9) * 8;
        bfrag8 r;
#pragma unroll
        for (int t = 0; t < 8; ++t) r[t] = (__bf16)W1[(kb + t) * 512 + n];
        *(bfrag8*)(W1T + n * 512 + kb) = r;
    } else if ((i -= S1E) < S2E) {          // W2: K=512, N=512
        int n = i & 511, kb = (i >> 9) * 8;
        bfrag8 r;
#pragma unroll
        for (int t = 0; t < 8; ++t) r[t] = (__bf16)W2[(kb + t) * 512 + n];
        *(bfrag8*)(W2T + n * 512 + kb) = r;
    } else if ((i -= S2E) < S3E) {          // W3: K=512, N=128
        int n = i & 127, kb = (i >> 7) * 8;
        bfrag8 r;
#pragma unroll
        for (int t = 0; t < 8; ++t) r[t] = (__bf16)W3[(kb + t) * 128 + n];
        *(bfrag8*)(W3T + n * 512 + kb) = r;
    } else if ((i -= S3E) < S4E) {          // Wl: K=128, N=256
        int n = i & 255, kb = (i >> 8) * 8;
        bfrag8 r;
#pragma unroll
        for (int t = 0; t < 8; ++t) r[t] = (__bf16)Wl[(kb + t) * 256 + n];
        *(bfrag8*)(WlT + n * 128 + kb) = r;
    } else if ((i -= S4E) < S5E) {          // Wr: K=512, N=256
        int n = i & 255, kb = (i >> 8) * 8;
        bfrag8 r;
#pragma unroll
        for (int t = 0; t < 8; ++t) r[t] = (__bf16)Wr[(kb + t) * 256 + n];
        *(bfrag8*)(WrT + n * 512 + kb) = r;
    } else if ((i -= S5E) < E) {
        atomicAdd(&deg[edst[i]], 1);
    }
}

// ---------------- CSR build ----------------

__global__ __launch_bounds__(256) void scan_kernel(const int* __restrict__ deg,
                                                   int* __restrict__ rowptr,
                                                   int* __restrict__ cursor, int n) {
    __shared__ int wtot[4], woff[4];
    int t = threadIdx.x, lane = t & 63, wv = t >> 6;
    int chunk = (n + 255) / 256;
    int beg = t * chunk, end = beg + chunk; if (end > n) end = n; if (beg > n) beg = n;
    int s = 0;
    for (int i = beg; i < end; ++i) s += deg[i] + 1;   // +1 self-loop
    int v = s;
#pragma unroll
    for (int off = 1; off < 64; off <<= 1) {
        int o = __shfl_up(v, off);
        if (lane >= off) v += o;
    }
    if (lane == 63) wtot[wv] = v;
    __syncthreads();
    if (t == 0) {
        int r = 0;
#pragma unroll
        for (int i = 0; i < 4; ++i) { woff[i] = r; r += wtot[i]; }
        rowptr[n] = r;
    }
    __syncthreads();
    int off = woff[wv] + v - s;     // exclusive prefix
    for (int i = beg; i < end; ++i) {
        rowptr[i] = off; cursor[i] = off;
        off += deg[i] + 1;
    }
}

__global__ __launch_bounds__(256) void scatter_kernel(const int* __restrict__ src,
                                                      const int* __restrict__ dst, int E, int n,
                                                      int* __restrict__ cursor,
                                                      int* __restrict__ csr) {
    int i = blockIdx.x * 256 + threadIdx.x;
    if (i < E) {
        int pos = atomicAdd(&cursor[dst[i]], 1);
        csr[pos] = src[i];
    } else if (i < E + n) {
        int v = i - E;
        int pos = atomicAdd(&cursor[v], 1);
        csr[pos] = v;                              // self-loop
    }
}

// ---------------- MFMA GEMM K-loop, BK=64, tile 128(M) x 16*NT(N) ----------------

template <int NT>
__device__ __forceinline__ void gemm_loop(const __bf16* __restrict__ A,
                                          const __bf16* __restrict__ BT, int K,
                                          int m0, int n0, int wave, int lane,
                                          __bf16* As, __bf16* Bs,
                                          floatx4 (&acc)[2][NT]) {
    int r = wave * 8 + (lane >> 3);          // 0..31 staging row
    int kof = (lane & 7) * 8;
    const __bf16* gA = A + (size_t)(m0 + r) * K + kof;
    const __bf16* gB = BT + (size_t)(n0 + r) * K + kof;
    __bf16* lA = As + r * 64 + kof;
    __bf16* lB = Bs + r * 64 + kof;
    const __bf16* fA = As + (wave * 32 + (lane & 15)) * 64 + (lane >> 4) * 8;
    const __bf16* fB = Bs + (lane & 15) * 64 + (lane >> 4) * 8;

    for (int k0 = 0; k0 < K; k0 += 64) {
#pragma unroll
        for (int u = 0; u < 4; ++u)
            __builtin_amdgcn_global_load_lds(
                (const __attribute__((address_space(1))) void*)(gA + (size_t)u * 32 * K),
                (__attribute__((address_space(3))) void*)(lA + u * 32 * 64), 16, 0, 0);
#pragma unroll
        for (int u = 0; u < NT / 2; ++u)
            __builtin_amdgcn_global_load_lds(
                (const __attribute__((address_space(1))) void*)(gB + (size_t)u * 32 * K),
                (__attribute__((address_space(3))) void*)(lB + u * 32 * 64), 16, 0, 0);
        gA += 64; gB += 64;
        __syncthreads();

#pragma unroll
        for (int ks = 0; ks < 2; ++ks) {
            bfrag8 a0 = *(const bfrag8*)(fA + ks * 32);
            bfrag8 a1 = *(const bfrag8*)(fA + 16 * 64 + ks * 32);
#pragma unroll
            for (int nt = 0; nt < NT; ++nt) {
                bfrag8 b = *(const bfrag8*)(fB + nt * 16 * 64 + ks * 32);
                acc[0][nt] = __builtin_amdgcn_mfma_f32_16x16x32_bf16(a0, b, acc[0][nt], 0, 0, 0);
                acc[1][nt] = __builtin_amdgcn_mfma_f32_16x16x32_bf16(a1, b, acc[1][nt], 0, 0, 0);
            }
        }
        __syncthreads();
    }
}

// GEMM: fp8 e4m3 out (for gather) + fused attn-logit PARTIALS (fp32-exact).
// 128x64 tile; grid (M_PAD/128, N/64) -- panel fast dim -> xcd = panel % 8 (L2 affinity).
// Partials interleaved: esp[(row*H+head)*2 + half], summed as float2 in gather_agg.
__global__ __launch_bounds__(256) void gemm_h(const __bf16* __restrict__ A,
                                              const __bf16* __restrict__ BT,
                                              unsigned char* __restrict__ C8,
                                              int N, int K, int H,
                                              const float* __restrict__ as_,
                                              const float* __restrict__ ad_,
                                              float* __restrict__ esp,
                                              float* __restrict__ edp) {
    __shared__ __align__(16) __bf16 As[128 * 64];
    __shared__ __align__(16) __bf16 Bs[64 * 64];
    int tid = threadIdx.x, wave = tid >> 6, lane = tid & 63;
    int m0 = blockIdx.x * 128, n0 = blockIdx.y * 64;
    floatx4 acc[2][4] = {};
    gemm_loop<4>(A, BT, K, m0, n0, wave, lane, As, Bs, acc);

    int crow = m0 + wave * 32 + (lane >> 4) * 4;
    int ccol = n0 + (lane & 15);
#pragma unroll
    for (int mt = 0; mt < 2; ++mt)
#pragma unroll
        for (int nt = 0; nt < 4; ++nt)
#pragma unroll
            for (int r = 0; r < 4; ++r) {
                float v = acc[mt][nt][r];
                size_t o = (size_t)(crow + mt * 16 + r) * N + ccol + nt * 16;
                int p = __builtin_amdgcn_cvt_pk_fp8_f32(v, v, 0, false);
                C8[o] = (unsigned char)(p & 0xff);
            }

    // fused logit partials: this block covers channels [(n0&64), (n0&64)+64) of head n0>>7
    int head = n0 >> 7;
    int half = (n0 >> 6) & 1;
    float a_sv[4], a_dv[4];
#pragma unroll
    for (int nt = 0; nt < 4; ++nt) {
        int cin = (n0 & 64) + nt * 16 + (lane & 15);
        a_sv[nt] = as_[head * 128 + cin];
        a_dv[nt] = ad_[head * 128 + cin];
    }
#pragma unroll
    for (int mt = 0; mt < 2; ++mt)
#pragma unroll
        for (int r = 0; r < 4; ++r) {
            float ps = 0.f, pd = 0.f;
#pragma unroll
            for (int nt = 0; nt < 4; ++nt) {
                float v = acc[mt][nt][r];
                ps += v * a_sv[nt];
                pd += v * a_dv[nt];
            }
#pragma unroll
            for (int off = 8; off; off >>= 1) {
                ps += __shfl_xor(ps, off);
                pd += __shfl_xor(pd, off);
            }
            if ((lane & 15) == 0) {
                int row = crow + mt * 16 + r;
                esp[(size_t)(row * H + head) * 2 + half] = ps;
                edp[(size_t)(row * H + head) * 2 + half] = pd;
            }
        }
}

// fused final: C = A1@B1T^T + A2@B2T^T + bias1 + bias2, fp32 out, rows < M
// grid (M_PAD/128, N/64), panel-fast for XCD affinity.
__global__ __launch_bounds__(256) void gemm_final(const __bf16* __restrict__ A1,
                                                  const __bf16* __restrict__ B1T, int K1,
                                                  const __bf16* __restrict__ A2,
                                                  const __bf16* __restrict__ B2T, int K2,
                                                  float* __restrict__ C,
                                                  const float* __restrict__ bias1,
                                                  const float* __restrict__ bias2,
                                                  int M, int N) {
    __shared__ __align__(16) __bf16 As[128 * 64];
    __shared__ __align__(16) __bf16 Bs[64 * 64];
    int tid = threadIdx.x, wave = tid >> 6, lane = tid & 63;
    int m0 = blockIdx.x * 128, n0 = blockIdx.y * 64;
    floatx4 acc[2][4] = {};
    gemm_loop<4>(A1, B1T, K1, m0, n0, wave, lane, As, Bs, acc);
    gemm_loop<4>(A2, B2T, K2, m0, n0, wave, lane, As, Bs, acc);

    int crow = m0 + wave * 32 + (lane >> 4) * 4;
    int ccol = n0 + (lane & 15);
#pragma unroll
    for (int mt = 0; mt < 2; ++mt)
#pragma unroll
        for (int nt = 0; nt < 4; ++nt)
#pragma unroll
            for (int r = 0; r < 4; ++r) {
                int row = crow + mt * 16 + r;
                int col = ccol + nt * 16;
                if (row < M)
                    C[(size_t)row * N + col] = acc[mt][nt][r] + bias1[col] + bias2[col];
            }
}

// ---------------- fused softmax + weighted gather, fp8 H, 8-way unrolled ----------------
// One wave per node, all heads. Main loop = R10 structure (no pipeline, <=64 VGPR).
// Serial tail replaced by ONE masked batched chunk reusing the same register buffers
// (clamped index, zero weight for pad slots) -- removes the dependent-iteration tail
// without changing the occupancy tier.

template <int H>
__global__ __launch_bounds__(256) void gather_agg(const unsigned char* __restrict__ H8,
                                                  const float* __restrict__ esp,
                                                  const float* __restrict__ edp,
                                                  const int* __restrict__ rowptr,
                                                  const int* __restrict__ csr,
                                                  const float* __restrict__ bias,
                                                  __bf16* __restrict__ outb) {
    constexpr int F = H * 128;
    constexpr int CH = F / 64;          // 8 or 2
    int wave = threadIdx.x >> 6, lane = threadIdx.x & 63;
    int node = blockIdx.x * 4 + wave;
    if (node >= M_PAD) return;
    int hsel = (H == 4) ? (lane >> 4) : 0;
    __bf16* op = outb + (size_t)node * F + lane * CH;
    if (node >= N_NODES) {
        if (H == 4) { bfrag8 z = {}; *(bfrag8*)op = z; }
        else        { bfrag2 z = {}; *(bfrag2*)op = z; }
        return;
    }
    const unsigned char* hp = H8 + lane * CH;
    const float2* es2 = (const float2*)esp;
    float2 dv = ((const float2*)edp)[node * H + hsel];
    float edv = dv.x + dv.y;
    int beg = rowptr[node], end = rowptr[node + 1];
    float acc[CH] = {};
    float wsum = 0.f;
    int j = beg;

    if constexpr (H == 4) {
        int s[8]; float2 e[8]; uint2 p[8];
        for (; j + 7 < end; j += 8) {
#pragma unroll
            for (int u = 0; u < 8; ++u) s[u] = csr[j + u];
#pragma unroll
            for (int u = 0; u < 8; ++u) e[u] = es2[s[u] * H + hsel];
#pragma unroll
            for (int u = 0; u < 8; ++u) p[u] = *(const uint2*)(hp + (size_t)s[u] * F);
#pragma unroll
            for (int u = 0; u < 8; ++u) {
                float t = e[u].x + e[u].y + edv;
                t = t > 0.f ? t : 0.2f * t;            // leaky_relu(0.2)
                float wgt = __expf(t);
                wsum += wgt;
                floatx2 f0 = __builtin_amdgcn_cvt_pk_f32_fp8(p[u].x, false);
                floatx2 f1 = __builtin_amdgcn_cvt_pk_f32_fp8(p[u].x, true);
                floatx2 f2 = __builtin_amdgcn_cvt_pk_f32_fp8(p[u].y, false);
                floatx2 f3 = __builtin_amdgcn_cvt_pk_f32_fp8(p[u].y, true);
                acc[0] += wgt * f0[0]; acc[1] += wgt * f0[1];
                acc[2] += wgt * f1[0]; acc[3] += wgt * f1[1];
                acc[4] += wgt * f2[0]; acc[5] += wgt * f2[1];
                acc[6] += wgt * f3[0]; acc[7] += wgt * f3[1];
            }
        }
        if (j < end) {                                  // masked tail chunk
#pragma unroll
            for (int u = 0; u < 8; ++u) s[u] = csr[(j + u < end) ? j + u : end - 1];
#pragma unroll
            for (int u = 0; u < 8; ++u) e[u] = es2[s[u] * H + hsel];
#pragma unroll
            for (int u = 0; u < 8; ++u) p[u] = *(const uint2*)(hp + (size_t)s[u] * F);
#pragma unroll
            for (int u = 0; u < 8; ++u) {
                float t = e[u].x + e[u].y + edv;
                t = t > 0.f ? t : 0.2f * t;
                float wgt = (j + u < end) ? __expf(t) : 0.f;
                wsum += wgt;
                floatx2 f0 = __builtin_amdgcn_cvt_pk_f32_fp8(p[u].x, false);
                floatx2 f1 = __builtin_amdgcn_cvt_pk_f32_fp8(p[u].x, true);
                floatx2 f2 = __builtin_amdgcn_cvt_pk_f32_fp8(p[u].y, false);
                floatx2 f3 = __builtin_amdgcn_cvt_pk_f32_fp8(p[u].y, true);
                acc[0] += wgt * f0[0]; acc[1] += wgt * f0[1];
                acc[2] += wgt * f1[0]; acc[3] += wgt * f1[1];
                acc[4] += wgt * f2[0]; acc[5] += wgt * f2[1];
                acc[6] += wgt * f3[0]; acc[7] += wgt * f3[1];
            }
        }
    } else {
        int s[8]; float2 e[8]; unsigned short p[8];
        for (; j + 7 < end; j += 8) {
#pragma unroll
            for (int u = 0; u < 8; ++u) s[u] = csr[j + u];
#pragma unroll
            for (int u = 0; u < 8; ++u) e[u] = es2[s[u] * H + hsel];
#pragma unroll
            for (int u = 0; u < 8; ++u) p[u] = *(const unsigned short*)(hp + (size_t)s[u] * F);
#pragma unroll
            for (int u = 0; u < 8; ++u) {
                float t = e[u].x + e[u].y + edv;
                t = t > 0.f ? t : 0.2f * t;
                float wgt = __expf(t);
                wsum += wgt;
                floatx2 f0 = __builtin_amdgcn_cvt_pk_f32_fp8((int)p[u], false);
                acc[0] += wgt * f0[0]; acc[1] += wgt * f0[1];
            }
        }
        if (j < end) {                                  // masked tail chunk
#pragma unroll
            for (int u = 0; u < 8; ++u) s[u] = csr[(j + u < end) ? j + u : end - 1];
#pragma unroll
            for (int u = 0; u < 8; ++u) e[u] = es2[s[u] * H + hsel];
#pragma unroll
            for (int u = 0; u < 8; ++u) p[u] = *(const unsigned short*)(hp + (size_t)s[u] * F);
#pragma unroll
            for (int u = 0; u < 8; ++u) {
                float t = e[u].x + e[u].y + edv;
                t = t > 0.f ? t : 0.2f * t;
                float wgt = (j + u < end) ? __expf(t) : 0.f;
                wsum += wgt;
                floatx2 f0 = __builtin_amdgcn_cvt_pk_f32_fp8((int)p[u], false);
                acc[0] += wgt * f0[0]; acc[1] += wgt * f0[1];
            }
        }
    }

    float inv = 1.f / (wsum + 1e-16f);
    if (H == 4) {
        bfrag8 r;
#pragma unroll
        for (int k = 0; k < 8; ++k) {
            float o = acc[k] * inv + bias[lane * 8 + k];
            o = o > 0.f ? o : __expf(o) - 1.f;     // ELU
            r[k] = (__bf16)o;
        }
        *(bfrag8*)op = r;
    } else {
        bfrag2 r;
#pragma unroll
        for (int k = 0; k < 2; ++k) {
            float o = acc[k] * inv + bias[lane * 2 + k];
            o = o > 0.f ? o : __expf(o) - 1.f;
            r[k] = (__bf16)o;
        }
        *(bfrag2*)op = r;
    }
}

// ---------------- launch ----------------

extern "C" void kernel_launch(void* const* d_in, const int* in_sizes, int n_in,
                              void* d_out, int out_size, void* d_ws, size_t ws_size,
                              hipStream_t stream) {
    const float* x   = (const float*)d_in[0];
    const float* W1  = (const float*)d_in[1];
    const float* a1s = (const float*)d_in[2];
    const float* a1d = (const float*)d_in[3];
    const float* b1  = (const float*)d_in[4];
    const float* W2  = (const float*)d_in[5];
    const float* a2s = (const float*)d_in[6];
    const float* a2d = (const float*)d_in[7];
    const float* b2  = (const float*)d_in[8];
    const float* W3  = (const float*)d_in[9];
    const float* a3s = (const float*)d_in[10];
    const float* a3d = (const float*)d_in[11];
    const float* b3  = (const float*)d_in[12];
    const float* Wl  = (const float*)d_in[13];
    const float* bl  = (const float*)d_in[14];
    const float* Wr  = (const float*)d_in[15];
    const float* br  = (const float*)d_in[16];
    const int*   ei  = (const int*)d_in[17];
    const int E = in_sizes[17] / 2;
    const int* esrc = ei;
    const int* edst = ei + E;
    const int slots = E + N_NODES;
    float* out = (float*)d_out;

    char* w = (char*)d_ws;
    auto alloc = [&](size_t b) { char* p = w; w += (b + 255) & ~(size_t)255; return p; };
    __bf16* xb  = (__bf16*)alloc((size_t)M_PAD * 512 * 2);
    __bf16* hb  = (__bf16*)alloc((size_t)M_PAD * 512 * 2);
    __bf16* hb3 = (__bf16*)alloc((size_t)M_PAD * 128 * 2);
    unsigned char* Hi8 = (unsigned char*)alloc((size_t)M_PAD * 512);
    __bf16* W1T = (__bf16*)alloc(512 * 512 * 2);
    __bf16* W2T = (__bf16*)alloc(512 * 512 * 2);
    __bf16* W3T = (__bf16*)alloc(128 * 512 * 2);
    __bf16* WlT = (__bf16*)alloc(256 * 128 * 2);
    __bf16* WrT = (__bf16*)alloc(256 * 512 * 2);
    float* esp    = (float*)alloc((size_t)2 * M_PAD * HEADS * 4);
    float* edp    = (float*)alloc((size_t)2 * M_PAD * HEADS * 4);
    int*   deg    = (int*)alloc(N_NODES * 4);
    int*   rowptr = (int*)alloc((N_NODES + 1) * 4);
    int*   cursor = (int*)alloc(N_NODES * 4);
    int*   csr    = (int*)alloc((size_t)slots * 4);

    (void)hipMemsetAsync(deg, 0, N_NODES * sizeof(int), stream);

    const int sp_total = S0V + S1E + S2E + S3E + S4E + S5E + E;
    prep<<<(sp_total + 255) / 256, 256, 0, stream>>>(x, W1, W2, W3, Wl, Wr, edst, E,
                                                     xb, W1T, W2T, W3T, WlT, WrT, deg);
    scan_kernel<<<1, 256, 0, stream>>>(deg, rowptr, cursor, N_NODES);
    scatter_kernel<<<(E + N_NODES + 255) / 256, 256, 0, stream>>>(esrc, edst, E, N_NODES,
                                                                  cursor, csr);

    // layer 1
    gemm_h<<<dim3(M_PAD / 128, 8), 256, 0, stream>>>(xb, W1T, Hi8, 512, 512, 4,
                                                     a1s, a1d, esp, edp);
    gather_agg<4><<<M_PAD / 4, 256, 0, stream>>>(Hi8, esp, edp, rowptr, csr, b1, hb);
    // layer 2
    gemm_h<<<dim3(M_PAD / 128, 8), 256, 0, stream>>>(hb, W2T, Hi8, 512, 512, 4,
                                                     a2s, a2d, esp, edp);
    gather_agg<4><<<M_PAD / 4, 256, 0, stream>>>(Hi8, esp, edp, rowptr, csr, b2, hb);
    // layer 3 (H=1)
    gemm_h<<<dim3(M_PAD / 128, 2), 256, 0, stream>>>(hb, W3T, Hi8, 128, 512, 1,
                                                     a3s, a3d, esp, edp);
    gather_agg<1><<<M_PAD / 4, 256, 0, stream>>>(Hi8, esp, edp, rowptr, csr, b3, hb3);
    // fused residual + final linear
    gemm_final<<<dim3(M_PAD / 128, 4), 256, 0, stream>>>(xb, WrT, 512, hb3, WlT, 128,
                                                         out, br, bl, N_NODES, 256);
}

// Round 14
// 259.606 us; speedup vs baseline: 1.0646x; 1.0285x over previous
//
#include <hip/hip_runtime.h>
#include <hip/hip_bf16.h>
#include <cstdint>
#include <cstddef>

#define N_NODES 10000
#define M_PAD   10240   // 80 panels of 128; 80 % 8 == 0 -> panel%8 = XCD under round-robin
#define HEADS   4

typedef __bf16 bfrag8 __attribute__((ext_vector_type(8)));
typedef __bf16 bfrag2 __attribute__((ext_vector_type(2)));
typedef float  floatx4 __attribute__((ext_vector_type(4)));
typedef float  floatx2 __attribute__((ext_vector_type(2)));

// ---------------- fused prep: x->bf16 pad, 5 weight transposes (8k per thread,
// 16B stores), edge degree count. deg[] zeroed by hipMemsetAsync beforehand. ----
#define S0V (M_PAD * 512 / 8)   // xb, 8 elements per thread
#define S1E (512 * 512 / 8)     // W1T
#define S2E (512 * 512 / 8)     // W2T
#define S3E (512 * 128 / 8)     // W3T
#define S4E (128 * 256 / 8)     // WlT
#define S5E (512 * 256 / 8)     // WrT

__global__ __launch_bounds__(256) void prep(const float* __restrict__ x,
                                            const float* __restrict__ W1,
                                            const float* __restrict__ W2,
                                            const float* __restrict__ W3,
                                            const float* __restrict__ Wl,
                                            const float* __restrict__ Wr,
                                            const int* __restrict__ edst, int E,
                                            __bf16* __restrict__ xb,
                                            __bf16* __restrict__ W1T,
                                            __bf16* __restrict__ W2T,
                                            __bf16* __restrict__ W3T,
                                            __bf16* __restrict__ WlT,
                                            __bf16* __restrict__ WrT,
                                            int* __restrict__ deg) {
    int i = blockIdx.x * 256 + threadIdx.x;
    if (i < S0V) {
        int base = i * 8;
        int row = base >> 9;
        bfrag8 r = {};
        if (row < N_NODES) {
            float4 f0 = ((const float4*)x)[i * 2];
            float4 f1 = ((const float4*)x)[i * 2 + 1];
            r[0] = (__bf16)f0.x; r[1] = (__bf16)f0.y; r[2] = (__bf16)f0.z; r[3] = (__bf16)f0.w;
            r[4] = (__bf16)f1.x; r[5] = (__bf16)f1.y; r[6] = (__bf16)f1.z; r[7] = (__bf16)f1.w;
        }
        *(bfrag8*)(xb + base) = r;
    } else if ((i -= S0V) < S1E) {          // W1: K=512, N=512
        int n = i & 511, kb = (i >> 9) * 8;
        bfrag8 r;
#pragma unroll
        for (int t = 0; t < 8; ++t) r[t] = (__bf16)W1[(kb + t) * 512 + n];
        *(bfrag8*)(W1T + n * 512 + kb) = r;
    } else if ((i -= S1E) < S2E) {          // W2: K=512, N=512
        int n = i & 511, kb = (i >> 9) * 8;
        bfrag8 r;
#pragma unroll
        for (int t = 0; t < 8; ++t) r[t] = (__bf16)W2[(kb + t) * 512 + n];
        *(bfrag8*)(W2T + n * 512 + kb) = r;
    } else if ((i -= S2E) < S3E) {          // W3: K=512, N=128
        int n = i & 127, kb = (i >> 7) * 8;
        bfrag8 r;
#pragma unroll
        for (int t = 0; t < 8; ++t) r[t] = (__bf16)W3[(kb + t) * 128 + n];
        *(bfrag8*)(W3T + n * 512 + kb) = r;
    } else if ((i -= S3E) < S4E) {          // Wl: K=128, N=256
        int n = i & 255, kb = (i >> 8) * 8;
        bfrag8 r;
#pragma unroll
        for (int t = 0; t < 8; ++t) r[t] = (__bf16)Wl[(kb + t) * 256 + n];
        *(bfrag8*)(WlT + n * 128 + kb) = r;
    } else if ((i -= S4E) < S5E) {          // Wr: K=512, N=256
        int n = i & 255, kb = (i >> 8) * 8;
        bfrag8 r;
#pragma unroll
        for (int t = 0; t < 8; ++t) r[t] = (__bf16)Wr[(kb + t) * 256 + n];
        *(bfrag8*)(WrT + n * 512 + kb) = r;
    } else if ((i -= S5E) < E) {
        atomicAdd(&deg[edst[i]], 1);
    }
}

// ---------------- CSR build ----------------

__global__ __launch_bounds__(256) void scan_kernel(const int* __restrict__ deg,
                                                   int* __restrict__ rowptr,
                                                   int* __restrict__ cursor, int n) {
    __shared__ int wtot[4], woff[4];
    int t = threadIdx.x, lane = t & 63, wv = t >> 6;
    int chunk = (n + 255) / 256;
    int beg = t * chunk, end = beg + chunk; if (end > n) end = n; if (beg > n) beg = n;
    int s = 0;
    for (int i = beg; i < end; ++i) s += deg[i] + 1;   // +1 self-loop
    int v = s;
#pragma unroll
    for (int off = 1; off < 64; off <<= 1) {
        int o = __shfl_up(v, off);
        if (lane >= off) v += o;
    }
    if (lane == 63) wtot[wv] = v;
    __syncthreads();
    if (t == 0) {
        int r = 0;
#pragma unroll
        for (int i = 0; i < 4; ++i) { woff[i] = r; r += wtot[i]; }
        rowptr[n] = r;
    }
    __syncthreads();
    int off = woff[wv] + v - s;     // exclusive prefix
    for (int i = beg; i < end; ++i) {
        rowptr[i] = off; cursor[i] = off;
        off += deg[i] + 1;
    }
}

__global__ __launch_bounds__(256) void scatter_kernel(const int* __restrict__ src,
                                                      const int* __restrict__ dst, int E, int n,
                                                      int* __restrict__ cursor,
                                                      int* __restrict__ csr) {
    int i = blockIdx.x * 256 + threadIdx.x;
    if (i < E) {
        int pos = atomicAdd(&cursor[dst[i]], 1);
        csr[pos] = src[i];
    } else if (i < E + n) {
        int v = i - E;
        int pos = atomicAdd(&cursor[v], 1);
        csr[pos] = v;                              // self-loop
    }
}

// ---------------- MFMA GEMM K-loop, BK=64, tile 128(M) x 16*NT(N) ----------------

template <int NT>
__device__ __forceinline__ void gemm_loop(const __bf16* __restrict__ A,
                                          const __bf16* __restrict__ BT, int K,
                                          int m0, int n0, int wave, int lane,
                                          __bf16* As, __bf16* Bs,
                                          floatx4 (&acc)[2][NT]) {
    int r = wave * 8 + (lane >> 3);          // 0..31 staging row
    int kof = (lane & 7) * 8;
    const __bf16* gA = A + (size_t)(m0 + r) * K + kof;
    const __bf16* gB = BT + (size_t)(n0 + r) * K + kof;
    __bf16* lA = As + r * 64 + kof;
    __bf16* lB = Bs + r * 64 + kof;
    const __bf16* fA = As + (wave * 32 + (lane & 15)) * 64 + (lane >> 4) * 8;
    const __bf16* fB = Bs + (lane & 15) * 64 + (lane >> 4) * 8;

    for (int k0 = 0; k0 < K; k0 += 64) {
#pragma unroll
        for (int u = 0; u < 4; ++u)
            __builtin_amdgcn_global_load_lds(
                (const __attribute__((address_space(1))) void*)(gA + (size_t)u * 32 * K),
                (__attribute__((address_space(3))) void*)(lA + u * 32 * 64), 16, 0, 0);
#pragma unroll
        for (int u = 0; u < NT / 2; ++u)
            __builtin_amdgcn_global_load_lds(
                (const __attribute__((address_space(1))) void*)(gB + (size_t)u * 32 * K),
                (__attribute__((address_space(3))) void*)(lB + u * 32 * 64), 16, 0, 0);
        gA += 64; gB += 64;
        __syncthreads();

#pragma unroll
        for (int ks = 0; ks < 2; ++ks) {
            bfrag8 a0 = *(const bfrag8*)(fA + ks * 32);
            bfrag8 a1 = *(const bfrag8*)(fA + 16 * 64 + ks * 32);
#pragma unroll
            for (int nt = 0; nt < NT; ++nt) {
                bfrag8 b = *(const bfrag8*)(fB + nt * 16 * 64 + ks * 32);
                acc[0][nt] = __builtin_amdgcn_mfma_f32_16x16x32_bf16(a0, b, acc[0][nt], 0, 0, 0);
                acc[1][nt] = __builtin_amdgcn_mfma_f32_16x16x32_bf16(a1, b, acc[1][nt], 0, 0, 0);
            }
        }
        __syncthreads();
    }
}

// GEMM: fp8 e4m3 out (for gather) + fused attn-logit PARTIALS (fp32-exact).
// 128x64 tile; grid (M_PAD/128, N/64) -- panel fast dim -> xcd = panel % 8 (L2 affinity).
// Partials: esp/edp[half][row][H], summed inside gather_agg.
__global__ __launch_bounds__(256) void gemm_h(const __bf16* __restrict__ A,
                                              const __bf16* __restrict__ BT,
                                              unsigned char* __restrict__ C8,
                                              int N, int K, int H,
                                              const float* __restrict__ as_,
                                              const float* __restrict__ ad_,
                                              float* __restrict__ esp,
                                              float* __restrict__ edp) {
    __shared__ __align__(16) __bf16 As[128 * 64];
    __shared__ __align__(16) __bf16 Bs[64 * 64];
    int tid = threadIdx.x, wave = tid >> 6, lane = tid & 63;
    int m0 = blockIdx.x * 128, n0 = blockIdx.y * 64;
    floatx4 acc[2][4] = {};
    gemm_loop<4>(A, BT, K, m0, n0, wave, lane, As, Bs, acc);

    int crow = m0 + wave * 32 + (lane >> 4) * 4;
    int ccol = n0 + (lane & 15);
#pragma unroll
    for (int mt = 0; mt < 2; ++mt)
#pragma unroll
        for (int nt = 0; nt < 4; ++nt)
#pragma unroll
            for (int r = 0; r < 4; ++r) {
                float v = acc[mt][nt][r];
                size_t o = (size_t)(crow + mt * 16 + r) * N + ccol + nt * 16;
                int p = __builtin_amdgcn_cvt_pk_fp8_f32(v, v, 0, false);
                C8[o] = (unsigned char)(p & 0xff);
            }

    // fused logit partials: this block covers channels [(n0&64), (n0&64)+64) of head n0>>7
    int head = n0 >> 7;
    int half = (n0 >> 6) & 1;
    float a_sv[4], a_dv[4];
#pragma unroll
    for (int nt = 0; nt < 4; ++nt) {
        int cin = (n0 & 64) + nt * 16 + (lane & 15);
        a_sv[nt] = as_[head * 128 + cin];
        a_dv[nt] = ad_[head * 128 + cin];
    }
    float* ep = esp + (size_t)half * M_PAD * H;
    float* dp = edp + (size_t)half * M_PAD * H;
#pragma unroll
    for (int mt = 0; mt < 2; ++mt)
#pragma unroll
        for (int r = 0; r < 4; ++r) {
            float ps = 0.f, pd = 0.f;
#pragma unroll
            for (int nt = 0; nt < 4; ++nt) {
                float v = acc[mt][nt][r];
                ps += v * a_sv[nt];
                pd += v * a_dv[nt];
            }
#pragma unroll
            for (int off = 8; off; off >>= 1) {
                ps += __shfl_xor(ps, off);
                pd += __shfl_xor(pd, off);
            }
            if ((lane & 15) == 0) {
                int row = crow + mt * 16 + r;
                ep[row * H + head] = ps;
                dp[row * H + head] = pd;
            }
        }
}

// fused final: C = A1@B1T^T + A2@B2T^T + bias1 + bias2, fp32 out, rows < M
// grid (M_PAD/128, N/64), panel-fast for XCD affinity.
__global__ __launch_bounds__(256) void gemm_final(const __bf16* __restrict__ A1,
                                                  const __bf16* __restrict__ B1T, int K1,
                                                  const __bf16* __restrict__ A2,
                                                  const __bf16* __restrict__ B2T, int K2,
                                                  float* __restrict__ C,
                                                  const float* __restrict__ bias1,
                                                  const float* __restrict__ bias2,
                                                  int M, int N) {
    __shared__ __align__(16) __bf16 As[128 * 64];
    __shared__ __align__(16) __bf16 Bs[64 * 64];
    int tid = threadIdx.x, wave = tid >> 6, lane = tid & 63;
    int m0 = blockIdx.x * 128, n0 = blockIdx.y * 64;
    floatx4 acc[2][4] = {};
    gemm_loop<4>(A1, B1T, K1, m0, n0, wave, lane, As, Bs, acc);
    gemm_loop<4>(A2, B2T, K2, m0, n0, wave, lane, As, Bs, acc);

    int crow = m0 + wave * 32 + (lane >> 4) * 4;
    int ccol = n0 + (lane & 15);
#pragma unroll
    for (int mt = 0; mt < 2; ++mt)
#pragma unroll
        for (int nt = 0; nt < 4; ++nt)
#pragma unroll
            for (int r = 0; r < 4; ++r) {
                int row = crow + mt * 16 + r;
                int col = ccol + nt * 16;
                if (row < M)
                    C[(size_t)row * N + col] = acc[mt][nt][r] + bias1[col] + bias2[col];
            }
}

// ---------------- fused softmax + weighted gather, fp8 H, 8-way unrolled ----------------
// One wave per node, all heads; logit partial sums (esp0+esp1) folded in here.
// R10 form: plain 8-chunks + serial tail; <=64 VGPR; latency hidden by TLP.

template <int H>
__global__ __launch_bounds__(256) void gather_agg(const unsigned char* __restrict__ H8,
                                                  const float* __restrict__ esp,
                                                  const float* __restrict__ edp,
                                                  const int* __restrict__ rowptr,
                                                  const int* __restrict__ csr,
                                                  const float* __restrict__ bias,
                                                  __bf16* __restrict__ outb) {
    constexpr int F = H * 128;
    constexpr int CH = F / 64;          // 8 or 2
    constexpr int PO = M_PAD * H;       // partial-plane offset
    int wave = threadIdx.x >> 6, lane = threadIdx.x & 63;
    int node = blockIdx.x * 4 + wave;
    if (node >= M_PAD) return;
    int hsel = (H == 4) ? (lane >> 4) : 0;
    __bf16* op = outb + (size_t)node * F + lane * CH;
    if (node >= N_NODES) {
        if (H == 4) { bfrag8 z = {}; *(bfrag8*)op = z; }
        else        { bfrag2 z = {}; *(bfrag2*)op = z; }
        return;
    }
    const unsigned char* hp = H8 + lane * CH;
    float edv = edp[node * H + hsel] + edp[PO + node * H + hsel];
    int beg = rowptr[node], end = rowptr[node + 1];
    float acc[CH] = {};
    float wsum = 0.f;
    int j = beg;
    for (; j + 7 < end; j += 8) {
        int s[8];
        float e[8];
#pragma unroll
        for (int u = 0; u < 8; ++u) s[u] = csr[j + u];
#pragma unroll
        for (int u = 0; u < 8; ++u)
            e[u] = esp[s[u] * H + hsel] + esp[PO + s[u] * H + hsel];
        if (H == 4) {
            uint2 p[8];
#pragma unroll
            for (int u = 0; u < 8; ++u) p[u] = *(const uint2*)(hp + (size_t)s[u] * F);
#pragma unroll
            for (int u = 0; u < 8; ++u) {
                float t = e[u] + edv;
                t = t > 0.f ? t : 0.2f * t;
                float wgt = __expf(t);
                wsum += wgt;
                floatx2 f0 = __builtin_amdgcn_cvt_pk_f32_fp8(p[u].x, false);
                floatx2 f1 = __builtin_amdgcn_cvt_pk_f32_fp8(p[u].x, true);
                floatx2 f2 = __builtin_amdgcn_cvt_pk_f32_fp8(p[u].y, false);
                floatx2 f3 = __builtin_amdgcn_cvt_pk_f32_fp8(p[u].y, true);
                acc[0] += wgt * f0[0]; acc[1] += wgt * f0[1];
                acc[2] += wgt * f1[0]; acc[3] += wgt * f1[1];
                acc[4] += wgt * f2[0]; acc[5] += wgt * f2[1];
                acc[6] += wgt * f3[0]; acc[7] += wgt * f3[1];
            }
        } else {
            unsigned short p[8];
#pragma unroll
            for (int u = 0; u < 8; ++u) p[u] = *(const unsigned short*)(hp + (size_t)s[u] * F);
#pragma unroll
            for (int u = 0; u < 8; ++u) {
                float t = e[u] + edv;
                t = t > 0.f ? t : 0.2f * t;
                float wgt = __expf(t);
                wsum += wgt;
                floatx2 f0 = __builtin_amdgcn_cvt_pk_f32_fp8((int)p[u], false);
                acc[0] += wgt * f0[0]; acc[1] += wgt * f0[1];
            }
        }
    }
    for (; j < end; ++j) {
        int s0 = csr[j];
        float t = esp[s0 * H + hsel] + esp[PO + s0 * H + hsel] + edv;
        t = t > 0.f ? t : 0.2f * t;
        float wgt = __expf(t);
        wsum += wgt;
        if (H == 4) {
            uint2 p = *(const uint2*)(hp + (size_t)s0 * F);
            floatx2 f0 = __builtin_amdgcn_cvt_pk_f32_fp8(p.x, false);
            floatx2 f1 = __builtin_amdgcn_cvt_pk_f32_fp8(p.x, true);
            floatx2 f2 = __builtin_amdgcn_cvt_pk_f32_fp8(p.y, false);
            floatx2 f3 = __builtin_amdgcn_cvt_pk_f32_fp8(p.y, true);
            acc[0] += wgt * f0[0]; acc[1] += wgt * f0[1];
            acc[2] += wgt * f1[0]; acc[3] += wgt * f1[1];
            acc[4] += wgt * f2[0]; acc[5] += wgt * f2[1];
            acc[6] += wgt * f3[0]; acc[7] += wgt * f3[1];
        } else {
            unsigned short p = *(const unsigned short*)(hp + (size_t)s0 * F);
            floatx2 f0 = __builtin_amdgcn_cvt_pk_f32_fp8((int)p, false);
            acc[0] += wgt * f0[0]; acc[1] += wgt * f0[1];
        }
    }
    float inv = 1.f / (wsum + 1e-16f);
    if (H == 4) {
        bfrag8 r;
#pragma unroll
        for (int k = 0; k < 8; ++k) {
            float o = acc[k] * inv + bias[lane * 8 + k];
            o = o > 0.f ? o : __expf(o) - 1.f;     // ELU
            r[k] = (__bf16)o;
        }
        *(bfrag8*)op = r;
    } else {
        bfrag2 r;
#pragma unroll
        for (int k = 0; k < 2; ++k) {
            float o = acc[k] * inv + bias[lane * 2 + k];
            o = o > 0.f ? o : __expf(o) - 1.f;
            r[k] = (__bf16)o;
        }
        *(bfrag2*)op = r;
    }
}

// ---------------- launch ----------------

extern "C" void kernel_launch(void* const* d_in, const int* in_sizes, int n_in,
                              void* d_out, int out_size, void* d_ws, size_t ws_size,
                              hipStream_t stream) {
    const float* x   = (const float*)d_in[0];
    const float* W1  = (const float*)d_in[1];
    const float* a1s = (const float*)d_in[2];
    const float* a1d = (const float*)d_in[3];
    const float* b1  = (const float*)d_in[4];
    const float* W2  = (const float*)d_in[5];
    const float* a2s = (const float*)d_in[6];
    const float* a2d = (const float*)d_in[7];
    const float* b2  = (const float*)d_in[8];
    const float* W3  = (const float*)d_in[9];
    const float* a3s = (const float*)d_in[10];
    const float* a3d = (const float*)d_in[11];
    const float* b3  = (const float*)d_in[12];
    const float* Wl  = (const float*)d_in[13];
    const float* bl  = (const float*)d_in[14];
    const float* Wr  = (const float*)d_in[15];
    const float* br  = (const float*)d_in[16];
    const int*   ei  = (const int*)d_in[17];
    const int E = in_sizes[17] / 2;
    const int* esrc = ei;
    const int* edst = ei + E;
    const int slots = E + N_NODES;
    float* out = (float*)d_out;

    char* w = (char*)d_ws;
    auto alloc = [&](size_t b) { char* p = w; w += (b + 255) & ~(size_t)255; return p; };
    __bf16* xb  = (__bf16*)alloc((size_t)M_PAD * 512 * 2);
    __bf16* hb  = (__bf16*)alloc((size_t)M_PAD * 512 * 2);
    __bf16* hb3 = (__bf16*)alloc((size_t)M_PAD * 128 * 2);
    unsigned char* Hi8 = (unsigned char*)alloc((size_t)M_PAD * 512);
    __bf16* W1T = (__bf16*)alloc(512 * 512 * 2);
    __bf16* W2T = (__bf16*)alloc(512 * 512 * 2);
    __bf16* W3T = (__bf16*)alloc(128 * 512 * 2);
    __bf16* WlT = (__bf16*)alloc(256 * 128 * 2);
    __bf16* WrT = (__bf16*)alloc(256 * 512 * 2);
    float* esp    = (float*)alloc((size_t)2 * M_PAD * HEADS * 4);
    float* edp    = (float*)alloc((size_t)2 * M_PAD * HEADS * 4);
    int*   deg    = (int*)alloc(N_NODES * 4);
    int*   rowptr = (int*)alloc((N_NODES + 1) * 4);
    int*   cursor = (int*)alloc(N_NODES * 4);
    int*   csr    = (int*)alloc((size_t)slots * 4);

    (void)hipMemsetAsync(deg, 0, N_NODES * sizeof(int), stream);

    const int sp_total = S0V + S1E + S2E + S3E + S4E + S5E + E;
    prep<<<(sp_total + 255) / 256, 256, 0, stream>>>(x, W1, W2, W3, Wl, Wr, edst, E,
                                                     xb, W1T, W2T, W3T, WlT, WrT, deg);
    scan_kernel<<<1, 256, 0, stream>>>(deg, rowptr, cursor, N_NODES);
    scatter_kernel<<<(E + N_NODES + 255) / 256, 256, 0, stream>>>(esrc, edst, E, N_NODES,
                                                                  cursor, csr);

    // layer 1
    gemm_h<<<dim3(M_PAD / 128, 8), 256, 0, stream>>>(xb, W1T, Hi8, 512, 512, 4,
                                                     a1s, a1d, esp, edp);
    gather_agg<4><<<M_PAD / 4, 256, 0, stream>>>(Hi8, esp, edp, rowptr, csr, b1, hb);
    // layer 2
    gemm_h<<<dim3(M_PAD / 128, 8), 256, 0, stream>>>(hb, W2T, Hi8, 512, 512, 4,
                                                     a2s, a2d, esp, edp);
    gather_agg<4><<<M_PAD / 4, 256, 0, stream>>>(Hi8, esp, edp, rowptr, csr, b2, hb);
    // layer 3 (H=1)
    gemm_h<<<dim3(M_PAD / 128, 2), 256, 0, stream>>>(hb, W3T, Hi8, 128, 512, 1,
                                                     a3s, a3d, esp, edp);
    gather_agg<1><<<M_PAD / 4, 256, 0, stream>>>(Hi8, esp, edp, rowptr, csr, b3, hb3);
    // fused residual + final linear
    gemm_final<<<dim3(M_PAD / 128, 4), 256, 0, stream>>>(xb, WrT, 512, hb3, WlT, 128,
                                                         out, br, bl, N_NODES, 256);
}